// Round 4
// baseline (185.855 us; speedup 1.0000x reference)
//
#include <hip/hip_runtime.h>
#include <stdint.h>

#define BATCH 256
#define INF   1024
#define OUTF  128
#define KD    8
#define NN    1024      // OUTF*KD
#define OROW  1152      // INF + OUTF

typedef __attribute__((ext_vector_type(8))) short short8;
typedef __attribute__((ext_vector_type(4))) float f32x4;

__device__ __forceinline__ unsigned short f2bf(float f) {
    union { float f; uint32_t u; } v; v.f = f;
    uint32_t r = v.u + 0x7FFFu + ((v.u >> 16) & 1u);   // RNE
    return (unsigned short)(r >> 16);
}

// Device-scope grid barrier. All 256 blocks resident (1/CU) by capacity.
// Release: per-wave vmcnt drain + L2 writeback (threadfence). Acquire: L2 inv.
// Bounded spin: a residency/visibility failure fails visibly, never hangs.
__device__ __forceinline__ void gridbar(unsigned int* cnt, int idx) {
    __threadfence();                       // release: drain stores, wb L2 -> L3
    __syncthreads();
    if (threadIdx.x == 0) {
        __hip_atomic_fetch_add(&cnt[idx], 1u, __ATOMIC_ACQ_REL,
                               __HIP_MEMORY_SCOPE_AGENT);
        unsigned int v = 0; int guard = 0;
        do {
            v = __hip_atomic_load(&cnt[idx], __ATOMIC_ACQUIRE,
                                  __HIP_MEMORY_SCOPE_AGENT);
            if (v >= 256u) break;
            __builtin_amdgcn_s_sleep(2);
        } while (++guard < (1 << 21));
    }
    __syncthreads();
    __threadfence();                       // acquire: invalidate stale L2 lines
}

// ws layout: Tt bf16[1024n][1024k] @0 (2MB) | xbf bf16[256][1024] @2MB (512KB)
//            M f32[256][1024] @2.5MB (1MB)  | counters @3.5MB (64B, memset 0)
__global__ __launch_bounds__(256) void mono_kernel(
    const float* __restrict__ x, const float* __restrict__ T,
    float* __restrict__ out, unsigned short* __restrict__ Tt,
    unsigned short* __restrict__ xbf, float* __restrict__ M,
    unsigned int* __restrict__ cnt)
{
    __shared__ union {
        unsigned short tr[64 * 65];                    // P0: 8.3 KB
        struct { float Mloc[256 * 12]; float red[256]; } p2;   // P2: 13.3 KB
    } sh;

    const int b = blockIdx.x;
    const int t = threadIdx.x;

    // ---------------- P0: T transpose+cvt, x cvt+copy ----------------
    {
        const int i0 = (b & 15) << 6;      // k-block of T
        const int n0 = (b >> 4) << 6;      // n-block of T
        const int tx = t & 63, ty = t >> 6;
        for (int r = ty; r < 64; r += 4)
            sh.tr[tx * 65 + r] = f2bf(T[(size_t)(i0 + r) * NN + n0 + tx]);

        // x row b: copy fp32 -> out, cvt bf16 -> xbf (independent of LDS)
        {
            const int j = t * 4;
            float4 v = *(const float4*)(x + (size_t)b * INF + j);
            *(float4*)(out + (size_t)b * OROW + j) = v;
            uint2 u;
            u.x = (uint32_t)f2bf(v.x) | ((uint32_t)f2bf(v.y) << 16);
            u.y = (uint32_t)f2bf(v.z) | ((uint32_t)f2bf(v.w) << 16);
            *(uint2*)(xbf + (size_t)b * INF + j) = u;
        }
        __syncthreads();
        #pragma unroll
        for (int p = 0; p < 8; ++p) {
            const int q = p * 512 + t * 2;
            const int n = q >> 6, i = q & 63;          // i even
            uint32_t u = (uint32_t)sh.tr[n * 65 + i]
                       | ((uint32_t)sh.tr[n * 65 + i + 1] << 16);
            *(uint32_t*)(Tt + (size_t)(n0 + n) * INF + i0 + i) = u;
        }
    }
    gridbar(cnt, 0);

    // ---------------- P1: M = xbf @ Tt^T (32x32 tile/block) ----------------
    {
        const int a0 = (b & 7) << 5;       // a-tile == XCD id: xbf stays L2-local
        const int n0 = (b >> 3) << 5;
        const int wave = t >> 6, lane = t & 63;
        const int rc = lane & 15, quad = lane >> 4;
        const int h = wave >> 1, g = wave & 1;
        const unsigned short* pa = xbf + (size_t)(a0 + h * 16 + rc) * INF + quad * 8;
        const unsigned short* pb = Tt  + (size_t)(n0 + g * 16 + rc) * INF + quad * 8;

        f32x4 acc0 = {0.f, 0.f, 0.f, 0.f}, acc1 = {0.f, 0.f, 0.f, 0.f};
        #pragma unroll 4
        for (int s = 0; s < 16; ++s) {
            short8 a0f = *(const short8*)(pa + (2 * s) * 32);
            short8 b0f = *(const short8*)(pb + (2 * s) * 32);
            short8 a1f = *(const short8*)(pa + (2 * s + 1) * 32);
            short8 b1f = *(const short8*)(pb + (2 * s + 1) * 32);
            acc0 = __builtin_amdgcn_mfma_f32_16x16x32_bf16(a0f, b0f, acc0, 0, 0, 0);
            acc1 = __builtin_amdgcn_mfma_f32_16x16x32_bf16(a1f, b1f, acc1, 0, 0, 0);
        }
        acc0[0] += acc1[0]; acc0[1] += acc1[1];
        acc0[2] += acc1[2]; acc0[3] += acc1[3];
        // C/D layout: col = lane&15, row = quad*4 + r  [m89/m91]
        #pragma unroll
        for (int r = 0; r < 4; ++r)
            M[(size_t)(a0 + h * 16 + quad * 4 + r) * NN + n0 + g * 16 + rc] = acc0[r];
    }
    gridbar(cnt, 1);

    // ---------------- P2: pair phase, block = (o, a-half) ----------------
    {
        const int o = b >> 1, ha = b & 1;
        // thread t stages M row t's 8-float slice for feature o
        const float* src = M + (size_t)t * NN + o * 8;
        f32x4 v0 = *(const f32x4*)(src);
        f32x4 v1 = *(const f32x4*)(src + 4);
        *(f32x4*)(sh.p2.Mloc + t * 12) = v0;
        *(f32x4*)(sh.p2.Mloc + t * 12 + 4) = v1;
        __syncthreads();

        const int ai = t & 127, hb = t >> 7;   // hb wave-uniform -> LDS broadcast
        const int a = ha * 128 + ai;
        f32x4 m0 = *(const f32x4*)(sh.p2.Mloc + a * 12);
        f32x4 m1 = *(const f32x4*)(sh.p2.Mloc + a * 12 + 4);
        float ssum = 0.f;
        #pragma unroll 4
        for (int j = 0; j < 128; ++j) {
            const float* mb = sh.p2.Mloc + (hb * 128 + j) * 12;
            f32x4 q0 = *(const f32x4*)(mb);
            f32x4 q1 = *(const f32x4*)(mb + 4);
            float d = fabsf(m0[0] - q0[0]) + fabsf(m0[1] - q0[1])
                    + fabsf(m0[2] - q0[2]) + fabsf(m0[3] - q0[3])
                    + fabsf(m1[0] - q1[0]) + fabsf(m1[1] - q1[1])
                    + fabsf(m1[2] - q1[2]) + fabsf(m1[3] - q1[3]);
            ssum += __expf(-d);
        }
        sh.p2.red[t] = ssum;
        __syncthreads();
        if (t < 128)   // self term exp(0)=1 cancelled by -1
            out[(size_t)(ha * 128 + t) * OROW + INF + o]
                = sh.p2.red[t] + sh.p2.red[t + 128] - 1.0f;
    }
}

extern "C" void kernel_launch(void* const* d_in, const int* in_sizes, int n_in,
                              void* d_out, int out_size, void* d_ws, size_t ws_size,
                              hipStream_t stream) {
    const float* x = (const float*)d_in[0];
    const float* T = (const float*)d_in[1];
    float* out = (float*)d_out;
    unsigned short* Tt  = (unsigned short*)d_ws;
    unsigned short* xbf = (unsigned short*)((char*)d_ws + (2u << 20));
    float*          M   = (float*)((char*)d_ws + (2u << 20) + (512u << 10));
    unsigned int*   cnt = (unsigned int*)((char*)d_ws + (3u << 20) + (512u << 10));

    hipMemsetAsync(cnt, 0, 64, stream);   // zero barrier counters (graph-legal)
    mono_kernel<<<256, 256, 0, stream>>>(x, T, out, Tt, xbf, M, cnt);
}

// Round 5
// 88.652 us; speedup vs baseline: 2.0965x; 2.0965x over previous
//
#include <hip/hip_runtime.h>
#include <stdint.h>

#define BATCH 256
#define INF   1024
#define OUTF  128
#define KD    8
#define NN    1024      // OUTF*KD
#define OROW  1152      // INF + OUTF

#define TSLS  1032      // Tsl row stride in shorts (16B-aligned, non-pow2)
#define MLS   12        // Mloc row stride in floats
#define CHW   8192      // f32 per x-chunk: 256 rows x 32 cols fp32 = 32 KB

typedef __attribute__((ext_vector_type(8))) short short8;
typedef __attribute__((ext_vector_type(4))) float f32x4;

__device__ __forceinline__ unsigned short f2bf(float f) {
    union { float f; uint32_t u; } v; v.f = f;
    uint32_t r = v.u + 0x7FFFu + ((v.u >> 16) & 1u);   // RNE
    return (unsigned short)(r >> 16);
}

// Pack 8 f32 -> 8 bf16 (RNE) via v_cvt_pk_bf16_f32 (2 elems/instr).
__device__ __forceinline__ short8 cvt8(f32x4 lo, f32x4 hi) {
    union { short8 s; uint32_t u[4]; } r;
    asm("v_cvt_pk_bf16_f32 %0, %1, %2" : "=v"(r.u[0]) : "v"(lo[0]), "v"(lo[1]));
    asm("v_cvt_pk_bf16_f32 %0, %1, %2" : "=v"(r.u[1]) : "v"(lo[2]), "v"(lo[3]));
    asm("v_cvt_pk_bf16_f32 %0, %1, %2" : "=v"(r.u[2]) : "v"(hi[0]), "v"(hi[1]));
    asm("v_cvt_pk_bf16_f32 %0, %1, %2" : "=v"(r.u[3]) : "v"(hi[2]), "v"(hi[3]));
    return r.s;
}

// DMA one 256x32 fp32 chunk of x into LDS. Linear LDS dest (1 KB per instr =
// 8 rows x 128 B); seg^(row&7) XOR applied on per-lane GLOBAL source (m173),
// so column reads of the 128 B-stride rows are bank-spread (2-way = free).
__device__ __forceinline__ void stage_x(
    const float* __restrict__ x, float* lbuf, int c, int wave, int lane)
{
    const int rin = lane >> 3;           // row within instr block (== row&7)
    const int seg = lane & 7;            // 16 B slot
    #pragma unroll
    for (int p = 0; p < 4; ++p) {
        const int i = wave * 4 + p;      // instr 0..31, wave-uniform
        const float* src = x + (size_t)(i * 8 + rin) * INF + c * 32 + ((seg ^ rin) << 2);
        float* dst = lbuf + i * 256;     // wave-uniform base + lane*16B
        __builtin_amdgcn_global_load_lds(
            (const __attribute__((address_space(1))) unsigned int*)src,
            (__attribute__((address_space(3))) unsigned int*)dst, 16, 0, 0);
    }
}

// One dispatch, no cross-block deps. Blocks 0..127: one output feature o each
// (T-slice stage -> DMA-pipelined slice GEMM -> LDS pair phase -> direct c write).
// Blocks 128..191: copy x -> out x-region.
__global__ __launch_bounds__(512) void mono_kernel(
    const float* __restrict__ x, const float* __restrict__ T,
    float* __restrict__ out)
{
    const int bid = blockIdx.x;
    const int t = threadIdx.x;

    if (bid >= OUTF) {                   // ---- x copy ----
        const int bx = bid - OUTF;       // 0..63
        const float4* xs = (const float4*)x;
        #pragma unroll
        for (int p = 0; p < 2; ++p) {
            int g = bx * 1024 + p * 512 + t;
            int row = g >> 8, col4 = g & 255;
            float4 v = xs[g];
            *(float4*)(out + (size_t)row * OROW + col4 * 4) = v;
        }
        return;
    }

    __shared__ __align__(16) float xls[3 * CHW];              // 96 KB triple buffer
    __shared__ __align__(16) unsigned short Tsl[KD * TSLS];   // 16.1 KB
    __shared__ __align__(16) float Mloc[256 * MLS];           // 12 KB
    __shared__ float red[2048];                               // 8 KB

    const int o = bid;
    const int wave = t >> 6, lane = t & 63;

    // Kick off DMA of chunks 0,1 immediately (overlaps T staging).
    stage_x(x, xls, 0, wave, lane);
    stage_x(x, xls + CHW, 1, wave, lane);

    // Stage T[:, o, :] -> Tsl[kd][k] bf16 (8 contiguous f32 per k).
    #pragma unroll
    for (int it = 0; it < 4; ++it) {
        int i = it * 512 + t;            // 0..2047 float4 units
        int k = i >> 1, h = (i & 1) * 4;
        float4 v = *(const float4*)(T + (size_t)k * NN + o * KD + h);
        Tsl[(h + 0) * TSLS + k] = f2bf(v.x);
        Tsl[(h + 1) * TSLS + k] = f2bf(v.y);
        Tsl[(h + 2) * TSLS + k] = f2bf(v.z);
        Tsl[(h + 3) * TSLS + k] = f2bf(v.w);
    }
    __syncthreads();   // Tsl ready (full drain also lands chunks 0,1 — once, ok)

    // ---- GEMM: wave w owns M rows [w*32, w*32+32), K pipelined in 32 chunks ----
    const int rc = lane & 15, quad = lane >> 4, r7 = rc & 7;
    const int abase = wave * 32;
    f32x4 acc0 = {0.f, 0.f, 0.f, 0.f}, acc1 = {0.f, 0.f, 0.f, 0.f};

    for (int c = 0; c < 32; ++c) {
        if (c == 31) { asm volatile("s_waitcnt vmcnt(0)" ::: "memory"); }
        else         { asm volatile("s_waitcnt vmcnt(4)" ::: "memory"); }
        __builtin_amdgcn_sched_barrier(0);
        __builtin_amdgcn_s_barrier();
        __builtin_amdgcn_sched_barrier(0);
        if (c + 2 < 32)
            stage_x(x, xls + ((c + 2) % 3) * CHW, c + 2, wave, lane);
        const float* xc = xls + (c % 3) * CHW;
        // A frags: rows abase+rc, abase+16+rc; k = c*32 + quad*8 .. +8
        const float* pr0 = xc + (abase + rc) * 32;
        const float* pr1 = pr0 + 16 * 32;
        f32x4 a0l = *(const f32x4*)(pr0 + (((2 * quad + 0) ^ r7) << 2));
        f32x4 a0h = *(const f32x4*)(pr0 + (((2 * quad + 1) ^ r7) << 2));
        f32x4 a1l = *(const f32x4*)(pr1 + (((2 * quad + 0) ^ r7) << 2));
        f32x4 a1h = *(const f32x4*)(pr1 + (((2 * quad + 1) ^ r7) << 2));
        short8 Bf = *(const short8*)(Tsl + r7 * TSLS + c * 32 + quad * 8);
        acc0 = __builtin_amdgcn_mfma_f32_16x16x32_bf16(cvt8(a0l, a0h), Bf, acc0, 0, 0, 0);
        acc1 = __builtin_amdgcn_mfma_f32_16x16x32_bf16(cvt8(a1l, a1h), Bf, acc1, 0, 0, 0);
    }

    // C/D layout: col = lane&15 (= kd, valid rc<8), row = quad*4 + r  [m89/m91]
    if (rc < 8) {
        #pragma unroll
        for (int r = 0; r < 4; ++r) {
            Mloc[(abase + quad * 4 + r) * MLS + rc]      = acc0[r];
            Mloc[(abase + 16 + quad * 4 + r) * MLS + rc] = acc1[r];
        }
    }
    __syncthreads();

    // ---- Pair phase: 4 a-rows x 32 b per thread, LDS-only ----
    const int g = t & 63, ob = t >> 6;   // ob wave-uniform -> LDS broadcast
    f32x4 m0[4], m1[4];
    #pragma unroll
    for (int ia = 0; ia < 4; ++ia) {
        const float* mp = Mloc + (ia * 64 + g) * MLS;
        m0[ia] = *(const f32x4*)(mp);
        m1[ia] = *(const f32x4*)(mp + 4);
    }
    float accs[4] = {0.f, 0.f, 0.f, 0.f};
    #pragma unroll 4
    for (int j = 0; j < 32; ++j) {
        const float* qp = Mloc + (ob * 32 + j) * MLS;
        f32x4 q0 = *(const f32x4*)(qp);
        f32x4 q1 = *(const f32x4*)(qp + 4);
        #pragma unroll
        for (int ia = 0; ia < 4; ++ia) {
            float d = fabsf(m0[ia][0] - q0[0]) + fabsf(m0[ia][1] - q0[1])
                    + fabsf(m0[ia][2] - q0[2]) + fabsf(m0[ia][3] - q0[3])
                    + fabsf(m1[ia][0] - q1[0]) + fabsf(m1[ia][1] - q1[1])
                    + fabsf(m1[ia][2] - q1[2]) + fabsf(m1[ia][3] - q1[3]);
            accs[ia] += __expf(-d);
        }
    }
    #pragma unroll
    for (int ia = 0; ia < 4; ++ia)
        red[(ob * 4 + ia) * 64 + g] = accs[ia];
    __syncthreads();
    if (t < 256) {
        int ia = t >> 6, gg = t & 63;
        float s = 0.f;
        #pragma unroll
        for (int ob2 = 0; ob2 < 8; ++ob2)
            s += red[(ob2 * 4 + ia) * 64 + gg];
        out[(size_t)(ia * 64 + gg) * OROW + INF + o] = s - 1.0f;  // -1 cancels self term
    }
}

extern "C" void kernel_launch(void* const* d_in, const int* in_sizes, int n_in,
                              void* d_out, int out_size, void* d_ws, size_t ws_size,
                              hipStream_t stream) {
    const float* x = (const float*)d_in[0];
    const float* T = (const float*)d_in[1];
    float* out = (float*)d_out;
    (void)d_ws; (void)ws_size;

    mono_kernel<<<OUTF + 64, 512, 0, stream>>>(x, T, out);
}

// Round 6
// 81.651 us; speedup vs baseline: 2.2762x; 1.0857x over previous
//
#include <hip/hip_runtime.h>
#include <stdint.h>

#define BATCH 256
#define INF   1024
#define OUTF  128
#define KD    8
#define NN    1024      // OUTF*KD
#define OROW  1152      // INF + OUTF

#define TSLS  1032      // Tsl row stride in shorts (16B-aligned, non-pow2)
#define MLS   12        // Mloc row stride in floats
#define CHW   8192      // f32 per x-chunk: 256 rows x 32 cols fp32 = 32 KB
#define NBUF  4         // chunk buffers (3 chunks in flight + 1 being read)

typedef __attribute__((ext_vector_type(8))) short short8;
typedef __attribute__((ext_vector_type(4))) float f32x4;

__device__ __forceinline__ unsigned short f2bf(float f) {
    union { float f; uint32_t u; } v; v.f = f;
    uint32_t r = v.u + 0x7FFFu + ((v.u >> 16) & 1u);   // RNE
    return (unsigned short)(r >> 16);
}

// Pack 8 f32 -> 8 bf16 (RNE) via v_cvt_pk_bf16_f32.
__device__ __forceinline__ short8 cvt8(f32x4 lo, f32x4 hi) {
    union { short8 s; uint32_t u[4]; } r;
    asm("v_cvt_pk_bf16_f32 %0, %1, %2" : "=v"(r.u[0]) : "v"(lo[0]), "v"(lo[1]));
    asm("v_cvt_pk_bf16_f32 %0, %1, %2" : "=v"(r.u[1]) : "v"(lo[2]), "v"(lo[3]));
    asm("v_cvt_pk_bf16_f32 %0, %1, %2" : "=v"(r.u[2]) : "v"(hi[0]), "v"(hi[1]));
    asm("v_cvt_pk_bf16_f32 %0, %1, %2" : "=v"(r.u[3]) : "v"(hi[2]), "v"(hi[3]));
    return r.s;
}

// DMA one 256x32 fp32 chunk of x into LDS. Wave w stages ONLY its own rows
// (w*32..w*32+32 -> LDS bytes w*4KB..(w+1)*4KB) and later reads ONLY those rows:
// the chunk pipeline is fully wave-private (no barrier needed, no cross-wave
// hazard). seg^(row&7) XOR applied on the per-lane GLOBAL source (m173).
__device__ __forceinline__ void stage_x(
    const float* __restrict__ x, float* lbuf, int c, int wave, int lane)
{
    const int rin = lane >> 3;           // row within instr block (== row&7)
    const int seg = lane & 7;            // 16 B slot
    #pragma unroll
    for (int p = 0; p < 4; ++p) {
        const int i = wave * 4 + p;      // instr 0..31, wave-uniform
        const float* src = x + (size_t)(i * 8 + rin) * INF + c * 32 + ((seg ^ rin) << 2);
        float* dst = lbuf + i * 256;     // wave-uniform base + lane*16B
        __builtin_amdgcn_global_load_lds(
            (const __attribute__((address_space(1))) unsigned int*)src,
            (__attribute__((address_space(3))) unsigned int*)dst, 16, 0, 0);
    }
}

// One dispatch, no cross-block deps. Blocks 0..127: one output feature o each.
// Blocks 128..191: copy x -> out x-region.
__global__ __launch_bounds__(512) void mono_kernel(
    const float* __restrict__ x, const float* __restrict__ T,
    float* __restrict__ out)
{
    const int bid = blockIdx.x;
    const int t = threadIdx.x;

    if (bid >= OUTF) {                   // ---- x copy ----
        const int bx = bid - OUTF;       // 0..63
        const float4* xs = (const float4*)x;
        #pragma unroll
        for (int p = 0; p < 2; ++p) {
            int g = bx * 1024 + p * 512 + t;
            int row = g >> 8, col4 = g & 255;
            float4 v = xs[g];
            *(float4*)(out + (size_t)row * OROW + col4 * 4) = v;
        }
        return;
    }

    __shared__ __align__(16) float xls[NBUF * CHW];           // 128 KB, 4 buffers
    __shared__ __align__(16) union {
        unsigned short Tsl[KD * TSLS];                        // GEMM phase (16.1 KB)
        float red[2048];                                      // pair phase (8 KB)
    } u;
    __shared__ __align__(16) float Mloc[256 * MLS];           // 12 KB

    const int o = bid;
    const int wave = t >> 6, lane = t & 63;

    // Prefetch chunks 0..2 (overlaps T staging; drained once by the syncthreads).
    stage_x(x, xls + 0 * CHW, 0, wave, lane);
    stage_x(x, xls + 1 * CHW, 1, wave, lane);
    stage_x(x, xls + 2 * CHW, 2, wave, lane);

    // Stage T[:, o, :] -> Tsl[kd][k] bf16 (8 contiguous f32 per k).
    #pragma unroll
    for (int it = 0; it < 4; ++it) {
        int i = it * 512 + t;            // 0..2047 float4 units
        int k = i >> 1, h = (i & 1) * 4;
        float4 v = *(const float4*)(T + (size_t)k * NN + o * KD + h);
        u.Tsl[(h + 0) * TSLS + k] = f2bf(v.x);
        u.Tsl[(h + 1) * TSLS + k] = f2bf(v.y);
        u.Tsl[(h + 2) * TSLS + k] = f2bf(v.z);
        u.Tsl[(h + 3) * TSLS + k] = f2bf(v.w);
    }
    __syncthreads();   // Tsl ready; also fully lands chunks 0..2 (once, at entry)

    // ---- GEMM: wave w owns M rows [w*32, w*32+32). BARRIER-FREE per-wave
    // pipeline, 3 chunks in flight, counted vmcnt (issue-early, T14). ----
    const int rc = lane & 15, quad = lane >> 4, r7 = rc & 7;
    const int abase = wave * 32;
    f32x4 acc0 = {0.f, 0.f, 0.f, 0.f}, acc1 = {0.f, 0.f, 0.f, 0.f};

    for (int c = 0; c < 32; ++c) {
        if (c <= 28) {
            stage_x(x, xls + ((c + 3) & 3) * CHW, c + 3, wave, lane);
            asm volatile("s_waitcnt vmcnt(12)" ::: "memory");   // chunk c landed
        } else if (c == 29) {
            asm volatile("s_waitcnt vmcnt(8)" ::: "memory");
        } else if (c == 30) {
            asm volatile("s_waitcnt vmcnt(4)" ::: "memory");
        } else {
            asm volatile("s_waitcnt vmcnt(0)" ::: "memory");
        }
        const float* xc = xls + (c & 3) * CHW;
        const float* pr0 = xc + (abase + rc) * 32;
        const float* pr1 = pr0 + 16 * 32;
        f32x4 a0l = *(const f32x4*)(pr0 + (((2 * quad + 0) ^ r7) << 2));
        f32x4 a0h = *(const f32x4*)(pr0 + (((2 * quad + 1) ^ r7) << 2));
        f32x4 a1l = *(const f32x4*)(pr1 + (((2 * quad + 0) ^ r7) << 2));
        f32x4 a1h = *(const f32x4*)(pr1 + (((2 * quad + 1) ^ r7) << 2));
        short8 Bf = *(const short8*)(u.Tsl + r7 * TSLS + c * 32 + quad * 8);
        acc0 = __builtin_amdgcn_mfma_f32_16x16x32_bf16(cvt8(a0l, a0h), Bf, acc0, 0, 0, 0);
        acc1 = __builtin_amdgcn_mfma_f32_16x16x32_bf16(cvt8(a1l, a1h), Bf, acc1, 0, 0, 0);
    }

    // C/D layout: col = lane&15 (= kd, valid rc<8), row = quad*4 + r  [m89/m91]
    if (rc < 8) {
        #pragma unroll
        for (int r = 0; r < 4; ++r) {
            Mloc[(abase + quad * 4 + r) * MLS + rc]      = acc0[r];
            Mloc[(abase + 16 + quad * 4 + r) * MLS + rc] = acc1[r];
        }
    }
    __syncthreads();   // Mloc ready; Tsl dead from here (union -> red)

    // ---- Pair phase: 4 a-rows x 32 b per thread, LDS-only ----
    const int g = t & 63, ob = t >> 6;   // ob wave-uniform -> LDS broadcast
    f32x4 m0[4], m1[4];
    #pragma unroll
    for (int ia = 0; ia < 4; ++ia) {
        const float* mp = Mloc + (ia * 64 + g) * MLS;
        m0[ia] = *(const f32x4*)(mp);
        m1[ia] = *(const f32x4*)(mp + 4);
    }
    float accs[4] = {0.f, 0.f, 0.f, 0.f};
    #pragma unroll 4
    for (int j = 0; j < 32; ++j) {
        const float* qp = Mloc + (ob * 32 + j) * MLS;
        f32x4 q0 = *(const f32x4*)(qp);
        f32x4 q1 = *(const f32x4*)(qp + 4);
        #pragma unroll
        for (int ia = 0; ia < 4; ++ia) {
            float d = fabsf(m0[ia][0] - q0[0]) + fabsf(m0[ia][1] - q0[1])
                    + fabsf(m0[ia][2] - q0[2]) + fabsf(m0[ia][3] - q0[3])
                    + fabsf(m1[ia][0] - q1[0]) + fabsf(m1[ia][1] - q1[1])
                    + fabsf(m1[ia][2] - q1[2]) + fabsf(m1[ia][3] - q1[3]);
            accs[ia] += __expf(-d);
        }
    }
    #pragma unroll
    for (int ia = 0; ia < 4; ++ia)
        u.red[(ob * 4 + ia) * 64 + g] = accs[ia];
    __syncthreads();
    if (t < 256) {
        int ia = t >> 6, gg = t & 63;
        float s = 0.f;
        #pragma unroll
        for (int ob2 = 0; ob2 < 8; ++ob2)
            s += u.red[(ob2 * 4 + ia) * 64 + gg];
        out[(size_t)(ia * 64 + gg) * OROW + INF + o] = s - 1.0f;  // -1 cancels self term
    }
}

extern "C" void kernel_launch(void* const* d_in, const int* in_sizes, int n_in,
                              void* d_out, int out_size, void* d_ws, size_t ws_size,
                              hipStream_t stream) {
    const float* x = (const float*)d_in[0];
    const float* T = (const float*)d_in[1];
    float* out = (float*)d_out;
    (void)d_ws; (void)ws_size;

    mono_kernel<<<OUTF + 64, 512, 0, stream>>>(x, T, out);
}

// Round 7
// 77.168 us; speedup vs baseline: 2.4084x; 1.0581x over previous
//
#include <hip/hip_runtime.h>
#include <stdint.h>

#define BATCH 256
#define INF   1024
#define OUTF  128
#define KD    8
#define NN    1024      // OUTF*KD
#define OROW  1152      // INF + OUTF

#define TSLS  1032      // Tsl row stride in shorts (16B-aligned, non-pow2)
#define MLS   12        // Mloc row stride in floats
#define CHW   8192      // f32 per x-chunk: 256 rows x 32 cols fp32 = 32 KB
#define NBUF  4         // chunk buffers (3 in flight + 1 being read)

typedef __attribute__((ext_vector_type(8))) short short8;
typedef __attribute__((ext_vector_type(4))) float f32x4;

__device__ __forceinline__ unsigned short f2bf(float f) {
    union { float f; uint32_t u; } v; v.f = f;
    uint32_t r = v.u + 0x7FFFu + ((v.u >> 16) & 1u);   // RNE
    return (unsigned short)(r >> 16);
}

// Pack 8 f32 -> 8 bf16 (RNE) via v_cvt_pk_bf16_f32.
__device__ __forceinline__ short8 cvt8(f32x4 lo, f32x4 hi) {
    union { short8 s; uint32_t u[4]; } r;
    asm("v_cvt_pk_bf16_f32 %0, %1, %2" : "=v"(r.u[0]) : "v"(lo[0]), "v"(lo[1]));
    asm("v_cvt_pk_bf16_f32 %0, %1, %2" : "=v"(r.u[1]) : "v"(lo[2]), "v"(lo[3]));
    asm("v_cvt_pk_bf16_f32 %0, %1, %2" : "=v"(r.u[2]) : "v"(hi[0]), "v"(hi[1]));
    asm("v_cvt_pk_bf16_f32 %0, %1, %2" : "=v"(r.u[3]) : "v"(hi[2]), "v"(hi[3]));
    return r.s;
}

// DMA one 256x32 fp32 chunk of x into LDS. Wave w stages ONLY its own rows
// (w*32..w*32+32 -> LDS bytes w*4KB..(w+1)*4KB) and later reads only those rows:
// the chunk pipeline is wave-private (no barrier). seg^(row&7) XOR applied on
// the per-lane GLOBAL source (m173) so swizzled b128 LDS reads are bank-clean.
__device__ __forceinline__ void stage_x(
    const float* __restrict__ x, float* lbuf, int c, int wave, int lane)
{
    const int rin = lane >> 3;           // row within instr block (== row&7)
    const int seg = lane & 7;            // 16 B slot
    #pragma unroll
    for (int p = 0; p < 4; ++p) {
        const int i = wave * 4 + p;      // instr 0..31, wave-uniform
        const float* src = x + (size_t)(i * 8 + rin) * INF + c * 32 + ((seg ^ rin) << 2);
        float* dst = lbuf + i * 256;     // wave-uniform base + lane*16B
        __builtin_amdgcn_global_load_lds(
            (const __attribute__((address_space(1))) unsigned int*)src,
            (__attribute__((address_space(3))) unsigned int*)dst, 16, 0, 0);
    }
}

// One GEMM K-step. ALL in-loop LDS reads are inside ONE asm block:
//   s_waitcnt vmcnt(VM) ; 5x ds_read_b128 ; s_waitcnt lgkmcnt(0)
// so hipcc sees no aliasing C-level LDS read and inserts NO vmcnt(0) drain
// (the R6 convoy). Outputs are live only after the trailing lgkmcnt (rule #18).
#define GEMM_STEP(c, VM) do {                                                 \
    const uint32_t bb = xlsBase + (uint32_t)((((c) & 3)) << 15);              \
    const uint32_t aT = tslBase + (uint32_t)((r7 * TSLS + (c) * 32 + quad * 8) << 1); \
    f32x4 a0l, a0h, a1l, a1h; short8 Bf;                                      \
    asm volatile(                                                             \
        "s_waitcnt vmcnt(" #VM ")\n\t"                                        \
        "ds_read_b128 %0, %5\n\t"                                             \
        "ds_read_b128 %1, %6\n\t"                                             \
        "ds_read_b128 %2, %7\n\t"                                             \
        "ds_read_b128 %3, %8\n\t"                                             \
        "ds_read_b128 %4, %9\n\t"                                             \
        "s_waitcnt lgkmcnt(0)"                                                \
        : "=v"(a0l), "=v"(a0h), "=v"(a1l), "=v"(a1h), "=v"(Bf)                \
        : "v"(bb + o00), "v"(bb + o01), "v"(bb + o10), "v"(bb + o11), "v"(aT) \
        : "memory");                                                          \
    acc0 = __builtin_amdgcn_mfma_f32_16x16x32_bf16(cvt8(a0l, a0h), Bf, acc0, 0, 0, 0); \
    acc1 = __builtin_amdgcn_mfma_f32_16x16x32_bf16(cvt8(a1l, a1h), Bf, acc1, 0, 0, 0); \
} while (0)

// One dispatch, no cross-block deps. Blocks 0..127: one output feature o each.
// Blocks 128..191: copy x -> out x-region.
__global__ __launch_bounds__(512) void mono_kernel(
    const float* __restrict__ x, const float* __restrict__ T,
    float* __restrict__ out)
{
    const int bid = blockIdx.x;
    const int t = threadIdx.x;

    if (bid >= OUTF) {                   // ---- x copy ----
        const int bx = bid - OUTF;       // 0..63
        const float4* xs = (const float4*)x;
        #pragma unroll
        for (int p = 0; p < 2; ++p) {
            int g = bx * 1024 + p * 512 + t;
            int row = g >> 8, col4 = g & 255;
            float4 v = xs[g];
            *(float4*)(out + (size_t)row * OROW + col4 * 4) = v;
        }
        return;
    }

    __shared__ __align__(16) float xls[NBUF * CHW];           // 128 KB, 4 buffers
    __shared__ __align__(16) union {
        unsigned short Tsl[KD * TSLS];                        // GEMM phase (16.1 KB)
        float red[2048];                                      // pair phase (8 KB)
    } u;
    __shared__ __align__(16) float Mloc[256 * MLS];           // 12 KB

    const int o = bid;
    const int wave = t >> 6, lane = t & 63;

    // Prefetch chunks 0..2 (overlaps T staging; drained once at the syncthreads).
    stage_x(x, xls + 0 * CHW, 0, wave, lane);
    stage_x(x, xls + 1 * CHW, 1, wave, lane);
    stage_x(x, xls + 2 * CHW, 2, wave, lane);

    // Stage T[:, o, :] -> Tsl[kd][k] bf16 (8 contiguous f32 per k).
    #pragma unroll
    for (int it = 0; it < 4; ++it) {
        int i = it * 512 + t;            // 0..2047 float4 units
        int k = i >> 1, h = (i & 1) * 4;
        float4 v = *(const float4*)(T + (size_t)k * NN + o * KD + h);
        u.Tsl[(h + 0) * TSLS + k] = f2bf(v.x);
        u.Tsl[(h + 1) * TSLS + k] = f2bf(v.y);
        u.Tsl[(h + 2) * TSLS + k] = f2bf(v.z);
        u.Tsl[(h + 3) * TSLS + k] = f2bf(v.w);
    }
    __syncthreads();   // Tsl ready; also fully lands chunks 0..2 (once, at entry)

    // ---- GEMM: wave w owns M rows [w*32, w*32+32). Barrier-free per-wave
    // pipeline, 3 chunks in flight, asm-gated counted vmcnt. ----
    const int rc = lane & 15, quad = lane >> 4, r7 = rc & 7;
    const int abase = wave * 32;
    f32x4 acc0 = {0.f, 0.f, 0.f, 0.f}, acc1 = {0.f, 0.f, 0.f, 0.f};

    // Per-lane LDS byte offsets (32-bit LDS addresses; HK pattern m201/m214).
    const uint32_t xlsBase = (uint32_t)(uintptr_t)(&xls[0]);
    const uint32_t tslBase = (uint32_t)(uintptr_t)(&u.Tsl[0]);
    const uint32_t offs0 = (uint32_t)((((2 * quad + 0) ^ r7)) << 4);
    const uint32_t offs1 = (uint32_t)((((2 * quad + 1) ^ r7)) << 4);
    const uint32_t rowA0 = (uint32_t)((abase + rc) * 128);
    const uint32_t o00 = rowA0 + offs0, o01 = rowA0 + offs1;
    const uint32_t o10 = rowA0 + 2048 + offs0, o11 = rowA0 + 2048 + offs1;

    for (int c = 0; c < 29; ++c) {
        stage_x(x, xls + ((c + 3) & 3) * CHW, c + 3, wave, lane);
        GEMM_STEP(c, 12);                // 16 outstanding -> chunk c landed
    }
    GEMM_STEP(29, 8);
    GEMM_STEP(30, 4);
    GEMM_STEP(31, 0);

    // C/D layout: col = lane&15 (= kd, valid rc<8), row = quad*4 + r  [m89/m91]
    if (rc < 8) {
        #pragma unroll
        for (int r = 0; r < 4; ++r) {
            Mloc[(abase + quad * 4 + r) * MLS + rc]      = acc0[r];
            Mloc[(abase + 16 + quad * 4 + r) * MLS + rc] = acc1[r];
        }
    }
    __syncthreads();   // Mloc ready; Tsl dead from here (union -> red)

    // ---- Pair phase: 4 a-rows x 32 b per thread, LDS-only ----
    const int g = t & 63, ob = t >> 6;   // ob wave-uniform -> LDS broadcast
    f32x4 m0[4], m1[4];
    #pragma unroll
    for (int ia = 0; ia < 4; ++ia) {
        const float* mp = Mloc + (ia * 64 + g) * MLS;
        m0[ia] = *(const f32x4*)(mp);
        m1[ia] = *(const f32x4*)(mp + 4);
    }
    float accs[4] = {0.f, 0.f, 0.f, 0.f};
    #pragma unroll 4
    for (int j = 0; j < 32; ++j) {
        const float* qp = Mloc + (ob * 32 + j) * MLS;
        f32x4 q0 = *(const f32x4*)(qp);
        f32x4 q1 = *(const f32x4*)(qp + 4);
        #pragma unroll
        for (int ia = 0; ia < 4; ++ia) {
            float d = fabsf(m0[ia][0] - q0[0]) + fabsf(m0[ia][1] - q0[1])
                    + fabsf(m0[ia][2] - q0[2]) + fabsf(m0[ia][3] - q0[3])
                    + fabsf(m1[ia][0] - q1[0]) + fabsf(m1[ia][1] - q1[1])
                    + fabsf(m1[ia][2] - q1[2]) + fabsf(m1[ia][3] - q1[3]);
            accs[ia] += __expf(-d);
        }
    }
    #pragma unroll
    for (int ia = 0; ia < 4; ++ia)
        u.red[(ob * 4 + ia) * 64 + g] = accs[ia];
    __syncthreads();
    if (t < 256) {
        int ia = t >> 6, gg = t & 63;
        float s = 0.f;
        #pragma unroll
        for (int ob2 = 0; ob2 < 8; ++ob2)
            s += u.red[(ob2 * 4 + ia) * 64 + gg];
        out[(size_t)(ia * 64 + gg) * OROW + INF + o] = s - 1.0f;  // -1 cancels self term
    }
}

extern "C" void kernel_launch(void* const* d_in, const int* in_sizes, int n_in,
                              void* d_out, int out_size, void* d_ws, size_t ws_size,
                              hipStream_t stream) {
    const float* x = (const float*)d_in[0];
    const float* T = (const float*)d_in[1];
    float* out = (float*)d_out;
    (void)d_ws; (void)ws_size;

    mono_kernel<<<OUTF + 64, 512, 0, stream>>>(x, T, out);
}

// Round 9
// 70.822 us; speedup vs baseline: 2.6243x; 1.0896x over previous
//
#include <hip/hip_runtime.h>
#include <stdint.h>

#define BATCH 256
#define INF   1024
#define OUTF  128
#define KD    8
#define NN    1024      // OUTF*KD
#define OROW  1152      // INF + OUTF

#define TSLP  1040      // Tsl row stride in shorts (2080 B row pitch)
#define MLS   12        // Mloc row stride in floats
#define CHSH  16384     // shorts per x-chunk: 256 rows x 64 bf16 = 32 KB
#define NBUF  4         // chunk buffers (3 in flight + 1 being read)

typedef __attribute__((ext_vector_type(8))) short short8;
typedef __attribute__((ext_vector_type(4))) float f32x4;

__device__ __forceinline__ unsigned short f2bf(float f) {
    union { float f; uint32_t u; } v; v.f = f;
    uint32_t r = v.u + 0x7FFFu + ((v.u >> 16) & 1u);   // RNE
    return (unsigned short)(r >> 16);
}

// K1 (R0-verified): T transpose-convert (blocks 0..255) -> Tt[n][k] bf16;
// x copy + bf16 convert (blocks 256..319).
__global__ __launch_bounds__(256) void prep_kernel(
    const float* __restrict__ x, const float* __restrict__ T,
    float* __restrict__ out, unsigned short* __restrict__ xbf,
    unsigned short* __restrict__ Tt)
{
    __shared__ unsigned short lds[64 * 65];
    int bid = blockIdx.x;
    int t = threadIdx.x;
    if (bid < 256) {
        int i0 = (bid >> 4) << 6;          // k-block
        int n0 = (bid & 15) << 6;          // n-block
        int tx = t & 63, ty = t >> 6;
        for (int r = ty; r < 64; r += 4) {
            float v = T[(size_t)(i0 + r) * NN + n0 + tx];
            lds[tx * 65 + r] = f2bf(v);    // lds[n_local][k_local]
        }
        __syncthreads();
        #pragma unroll
        for (int p = 0; p < 8; ++p) {
            int q = p * 512 + t * 2;
            int n = q >> 6, i = q & 63;    // i even
            uint32_t u = (uint32_t)lds[n * 65 + i] | ((uint32_t)lds[n * 65 + i + 1] << 16);
            *(uint32_t*)(Tt + (size_t)(n0 + n) * INF + i0 + i) = u;
        }
    } else {
        int bx = bid - 256;                // 0..63
        #pragma unroll
        for (int p = 0; p < 4; ++p) {
            int a = bx * 4 + p;
            int j = t * 4;
            float4 v = *(const float4*)(x + (size_t)a * INF + j);
            *(float4*)(out + (size_t)a * OROW + j) = v;
            uint2 u;
            u.x = (uint32_t)f2bf(v.x) | ((uint32_t)f2bf(v.y) << 16);
            u.y = (uint32_t)f2bf(v.z) | ((uint32_t)f2bf(v.w) << 16);
            *(uint2*)(xbf + (size_t)a * INF + j) = u;
        }
    }
}

// DMA one 256x64 bf16 chunk of xbf into LDS. Wave w stages ONLY rows
// [32w,32w+32) (LDS bytes [4KB*w,4KB*(w+1))) and later reads only those rows:
// wave-private pipeline, no barrier. seg^(row&7) XOR on the GLOBAL src (m173).
__device__ __forceinline__ void stage_xb(
    const unsigned short* __restrict__ xbf, unsigned short* lbuf,
    int c, int wave, int lane)
{
    const int rin = lane >> 3;             // row within 8-row instr block
    const int seg = lane & 7;              // 16 B slot (8 bf16)
    #pragma unroll
    for (int p = 0; p < 4; ++p) {
        const int i = wave * 4 + p;        // instr 0..31
        const unsigned short* src = xbf + (size_t)(i * 8 + rin) * INF
                                        + c * 64 + ((seg ^ rin) << 3);
        unsigned short* dst = lbuf + i * 512;   // 1 KB per instr, linear
        __builtin_amdgcn_global_load_lds(
            (const __attribute__((address_space(1))) unsigned int*)src,
            (__attribute__((address_space(3))) unsigned int*)dst, 16, 0, 0);
    }
}

// One K=64 GEMM step: all LDS reads in ONE asm block (vmcnt gate + 6x
// ds_read_b128 + lgkmcnt(0)) so hipcc inserts no vmcnt(0) drain (R7-proven).
#define GEMM_STEP(c, VM) do {                                                 \
    const uint32_t bb = xlsBase + (uint32_t)(((c) & 3) << 15);                \
    const uint32_t tb = tslBase + (uint32_t)((c) << 7);                       \
    short8 A00, A01, A10, A11, B0, B1;                                        \
    asm volatile(                                                             \
        "s_waitcnt vmcnt(" #VM ")\n\t"                                        \
        "ds_read_b128 %0, %6\n\t"                                             \
        "ds_read_b128 %1, %7\n\t"                                             \
        "ds_read_b128 %2, %8\n\t"                                             \
        "ds_read_b128 %3, %9\n\t"                                             \
        "ds_read_b128 %4, %10\n\t"                                            \
        "ds_read_b128 %5, %11\n\t"                                            \
        "s_waitcnt lgkmcnt(0)"                                                \
        : "=v"(A00), "=v"(A01), "=v"(A10), "=v"(A11), "=v"(B0), "=v"(B1)      \
        : "v"(bb + oA00), "v"(bb + oA01), "v"(bb + oA10), "v"(bb + oA11),     \
          "v"(tb + oB0), "v"(tb + oB1)                                        \
        : "memory");                                                          \
    acc0 = __builtin_amdgcn_mfma_f32_16x16x32_bf16(A00, B0, acc0, 0, 0, 0);   \
    acc0 = __builtin_amdgcn_mfma_f32_16x16x32_bf16(A01, B1, acc0, 0, 0, 0);   \
    acc1 = __builtin_amdgcn_mfma_f32_16x16x32_bf16(A10, B0, acc1, 0, 0, 0);   \
    acc1 = __builtin_amdgcn_mfma_f32_16x16x32_bf16(A11, B1, acc1, 0, 0, 0);   \
} while (0)

// K2: 256 blocks = (o, a-half). GEMM for full M[:,o] (bf16 DMA pipeline),
// pair phase for this block's 128 a-rows, direct c write.
__global__ __launch_bounds__(512, 1) void fused_kernel(
    const unsigned short* __restrict__ xbf, const unsigned short* __restrict__ Tt,
    float* __restrict__ out)
{
    __shared__ __align__(16) unsigned short xls[NBUF * CHSH];   // 128 KB
    __shared__ __align__(16) union {
        unsigned short Tsl[KD * TSLP];                          // 16.25 KB (GEMM)
        float red[512];                                         // 2 KB (pair)
    } u;
    __shared__ __align__(16) float Mloc[256 * MLS];             // 12 KB
    // total 160000 B <= 160 KiB -> 1 block/CU

    const int o = blockIdx.x >> 1;
    const int half = blockIdx.x & 1;
    const int t = threadIdx.x;
    const int wave = t >> 6, lane = t & 63;

    // Stage Tsl: Tt rows 8o..8o+8 -> padded rows (2 instrs/wave; kd = wave).
    #pragma unroll
    for (int p = 0; p < 2; ++p) {
        const unsigned short* src = Tt + (size_t)(o * 8 + wave) * INF + p * 512 + lane * 8;
        unsigned short* dst = u.Tsl + wave * TSLP + p * 512;
        __builtin_amdgcn_global_load_lds(
            (const __attribute__((address_space(1))) unsigned int*)src,
            (__attribute__((address_space(3))) unsigned int*)dst, 16, 0, 0);
    }
    // Prefetch x chunks 0..2 (drained once by the entry barrier).
    stage_xb(xbf, xls + 0 * CHSH, 0, wave, lane);
    stage_xb(xbf, xls + 1 * CHSH, 1, wave, lane);
    stage_xb(xbf, xls + 2 * CHSH, 2, wave, lane);
    __syncthreads();   // drains all DMA (Tsl visible to all waves)

    // ---- GEMM: wave w owns M rows [32w,32w+32); 16 K-chunks, depth-3 ----
    const int rc = lane & 15, quad = lane >> 4, r7 = rc & 7;
    const int abase = wave * 32;
    f32x4 acc0 = {0.f, 0.f, 0.f, 0.f}, acc1 = {0.f, 0.f, 0.f, 0.f};

    const uint32_t xlsBase = (uint32_t)(uintptr_t)(&xls[0]);
    const uint32_t tslBase = (uint32_t)(uintptr_t)(&u.Tsl[0]);
    const uint32_t rowA = (uint32_t)((abase + rc) * 128);
    const uint32_t oA00 = rowA + (uint32_t)(((0 * 4 + quad) ^ r7) << 4);
    const uint32_t oA01 = rowA + (uint32_t)(((1 * 4 + quad) ^ r7) << 4);
    const uint32_t oA10 = oA00 + 2048, oA11 = oA01 + 2048;
    const uint32_t oB0 = (uint32_t)(r7 * 2080 + quad * 16);
    const uint32_t oB1 = oB0 + 64;

    for (int c = 0; c < 13; ++c) {
        stage_xb(xbf, xls + ((c + 3) & 3) * CHSH, c + 3, wave, lane);
        GEMM_STEP(c, 12);              // 16 outstanding -> chunk c landed
    }
    GEMM_STEP(13, 8);
    GEMM_STEP(14, 4);
    GEMM_STEP(15, 0);

    // C/D layout: col = lane&15 (= kd, valid rc<8), row = quad*4 + r [m89/m91]
    if (rc < 8) {
        #pragma unroll
        for (int r = 0; r < 4; ++r) {
            Mloc[(abase + quad * 4 + r) * MLS + rc]      = acc0[r];
            Mloc[(abase + 16 + quad * 4 + r) * MLS + rc] = acc1[r];
        }
    }
    __syncthreads();   // Mloc ready; Tsl dead (union -> red)

    // ---- Pair phase: this block's 128 a-rows x all 256 b ----
    const int ar = t & 127;            // a-row within half
    const int bq = t >> 7;             // 0..3, wave-uniform -> LDS broadcast
    const int a = half * 128 + ar;
    f32x4 m0 = *(const f32x4*)(Mloc + a * MLS);
    f32x4 m1 = *(const f32x4*)(Mloc + a * MLS + 4);
    float ssum = 0.f;
    #pragma unroll 4
    for (int j = 0; j < 64; ++j) {
        const float* qp = Mloc + (bq * 64 + j) * MLS;
        f32x4 q0 = *(const f32x4*)(qp);
        f32x4 q1 = *(const f32x4*)(qp + 4);
        float d = fabsf(m0[0] - q0[0]) + fabsf(m0[1] - q0[1])
                + fabsf(m0[2] - q0[2]) + fabsf(m0[3] - q0[3])
                + fabsf(m1[0] - q1[0]) + fabsf(m1[1] - q1[1])
                + fabsf(m1[2] - q1[2]) + fabsf(m1[3] - q1[3]);
        ssum += __expf(-d);
    }
    u.red[t] = ssum;
    __syncthreads();
    if (t < 128) {
        float s = u.red[t] + u.red[t + 128] + u.red[t + 256] + u.red[t + 384];
        out[(size_t)(half * 128 + t) * OROW + INF + o] = s - 1.0f;  // -1 = self term
    }
}

extern "C" void kernel_launch(void* const* d_in, const int* in_sizes, int n_in,
                              void* d_out, int out_size, void* d_ws, size_t ws_size,
                              hipStream_t stream) {
    const float* x = (const float*)d_in[0];
    const float* T = (const float*)d_in[1];
    float* out = (float*)d_out;
    unsigned short* xbf = (unsigned short*)d_ws;                       // 512 KB
    unsigned short* Tt  = (unsigned short*)((char*)d_ws + 524288);     // 2 MB

    prep_kernel<<<320, 256, 0, stream>>>(x, T, out, xbf, Tt);
    fused_kernel<<<256, 512, 0, stream>>>(xbf, Tt, out);
}